// Round 1
// baseline (151.358 us; speedup 1.0000x reference)
//
#include <hip/hip_runtime.h>
#include <math.h>

// Circle GIoU loss, summed over N pairs.
// x, y: (N,3) float32 row-major [cx, cy, r]. Output: scalar float32 sum.

#define EPSF   1e-07f
#define ACLIPF (1.0f - 1e-06f)
#define PIF    3.14159265358979323846f

__device__ __forceinline__ float circle_giou(float cx0, float cy0, float r0,
                                             float cx1, float cy1, float r1) {
    float dx = cx0 - cx1, dy = cy0 - cy1;
    float d2 = dx * dx + dy * dy;
    float d  = sqrtf(fmaxf(d2, EPSF));
    float rmax = fmaxf(r0, r1), rmin = fminf(r0, r1);
    float rdiff = rmax - rmin;
    bool lens      = (d < r0 + r1) && (d > rdiff);
    bool contained = (d <= rdiff);

    float r0s = r0 * r0, r1s = r1 * r1;
    float cos0 = fminf(fmaxf((d2 + r0s - r1s) / fmaxf(2.0f * d * r0, EPSF), -ACLIPF), ACLIPF);
    float cos1 = fminf(fmaxf((d2 + r1s - r0s) / fmaxf(2.0f * d * r1, EPSF), -ACLIPF), ACLIPF);
    float t = (r0 + r1 - d) * (d + r0 - r1) * (d - r0 + r1) * (d + r0 + r1);
    float t_safe = lens ? fmaxf(t, EPSF) : 1.0f;
    float lens_area = r0s * acosf(cos0) + r1s * acosf(cos1) - 0.5f * sqrtf(t_safe);
    float inter = lens ? lens_area : (contained ? PIF * rmin * rmin : 0.0f);
    float uni = PIF * (r0s + r1s) - inter;
    float iou = inter / fmaxf(uni, EPSF);

    float alpha = acosf(fminf(fmaxf(rdiff / d, 0.0f), ACLIPF));
    float h2 = d2 - rdiff * rdiff;
    float h2_safe = contained ? 1.0f : fmaxf(h2, EPSF);
    float hull_open = rmax * rmax * (PIF - alpha) + rmin * rmin * alpha
                      + (rmax + rmin) * sqrtf(h2_safe);
    float hull = contained ? PIF * rmax * rmax : hull_open;

    return 1.0f - (iou - (hull - uni) / fmaxf(hull, EPSF));
}

__global__ __launch_bounds__(256)
void GIOULOSS_19524921327670_kernel(const float4* __restrict__ x4,
                                    const float4* __restrict__ y4,
                                    float* __restrict__ out, int ngroups) {
    int g = blockIdx.x * blockDim.x + threadIdx.x;
    float acc = 0.0f;
    if (g < ngroups) {
        // 4 elements (12 floats) per thread via 3 coalesced float4 loads each input
        float4 xa = x4[3 * g + 0], xb = x4[3 * g + 1], xc = x4[3 * g + 2];
        float4 ya = y4[3 * g + 0], yb = y4[3 * g + 1], yc = y4[3 * g + 2];
        acc += circle_giou(xa.x, xa.y, xa.z,  ya.x, ya.y, ya.z);
        acc += circle_giou(xa.w, xb.x, xb.y,  ya.w, yb.x, yb.y);
        acc += circle_giou(xb.z, xb.w, xc.x,  yb.z, yb.w, yc.x);
        acc += circle_giou(xc.y, xc.z, xc.w,  yc.y, yc.z, yc.w);
    }

    // wave-64 shuffle reduction
    #pragma unroll
    for (int off = 32; off > 0; off >>= 1)
        acc += __shfl_down(acc, off, 64);

    __shared__ float wave_sums[4];  // 256 threads / 64 = 4 waves
    int lane = threadIdx.x & 63;
    int wave = threadIdx.x >> 6;
    if (lane == 0) wave_sums[wave] = acc;
    __syncthreads();
    if (threadIdx.x == 0) {
        float s = wave_sums[0] + wave_sums[1] + wave_sums[2] + wave_sums[3];
        atomicAdd(out, s);
    }
}

extern "C" void kernel_launch(void* const* d_in, const int* in_sizes, int n_in,
                              void* d_out, int out_size, void* d_ws, size_t ws_size,
                              hipStream_t stream) {
    const float4* x4 = (const float4*)d_in[0];
    const float4* y4 = (const float4*)d_in[1];
    float* out = (float*)d_out;

    int n = in_sizes[0] / 3;          // number of circle pairs (4194304)
    int ngroups = n / 4;              // 4 elements per thread (N divisible by 4)

    hipMemsetAsync(out, 0, sizeof(float), stream);

    int block = 256;
    int grid = (ngroups + block - 1) / block;
    GIOULOSS_19524921327670_kernel<<<grid, block, 0, stream>>>(x4, y4, out, ngroups);
}

// Round 2
// 150.159 us; speedup vs baseline: 1.0080x; 1.0080x over previous
//
#include <hip/hip_runtime.h>
#include <math.h>

// Circle GIoU loss, summed over N pairs.
// x, y: (N,3) float32 row-major [cx, cy, r]. Output: scalar float32 sum.
//
// Fast-math version: v_rcp_f32 / v_sqrt_f32 builtins + polynomial acos.
// Accuracy budget: harness threshold is 2% of the ~3.7e6 sum; acos poly
// abs err 6.7e-5 rad and rcp ~1e-6 rel err contribute O(100) absolute.

#define EPSF   1e-07f
#define ACLIPF (1.0f - 1e-06f)
#define PIF    3.14159265358979323846f

__device__ __forceinline__ float frcp(float x)  { return __builtin_amdgcn_rcpf(x); }
__device__ __forceinline__ float fsqrt(float x) { return __builtin_amdgcn_sqrtf(x); }

// Abramowitz & Stegun 4.4.45: acos(x) ~ sqrt(1-x)*poly(x), x in [0,1]; abs err < 6.7e-5
__device__ __forceinline__ float fast_acos(float x) {
    float ax = fabsf(x);
    float p = fmaf(fmaf(fmaf(-0.0187293f, ax, 0.0742610f), ax, -0.2121144f), ax, 1.5707288f);
    float r = fsqrt(1.0f - ax) * p;
    return x < 0.0f ? PIF - r : r;
}

__device__ __forceinline__ float circle_giou(float cx0, float cy0, float r0,
                                             float cx1, float cy1, float r1) {
    float dx = cx0 - cx1, dy = cy0 - cy1;
    float d2 = fmaf(dx, dx, dy * dy);
    float d  = fsqrt(fmaxf(d2, EPSF));
    float rmax = fmaxf(r0, r1), rmin = fminf(r0, r1);
    float rdiff = rmax - rmin, rsum = r0 + r1;
    bool lens      = (d < rsum) && (d > rdiff);
    bool contained = (d <= rdiff);

    float r0s = r0 * r0, r1s = r1 * r1;
    float inv0 = frcp(fmaxf(2.0f * d * r0, EPSF));
    float inv1 = frcp(fmaxf(2.0f * d * r1, EPSF));
    float cos0 = fminf(fmaxf((d2 + r0s - r1s) * inv0, -ACLIPF), ACLIPF);
    float cos1 = fminf(fmaxf((d2 + r1s - r0s) * inv1, -ACLIPF), ACLIPF);

    // Heron product via difference of squares: ((r0+r1)^2-d2)*(d2-(r0-r1)^2)
    float t = (rsum * rsum - d2) * (d2 - rdiff * rdiff);
    float t_safe = lens ? fmaxf(t, EPSF) : 1.0f;
    float lens_area = r0s * fast_acos(cos0) + r1s * fast_acos(cos1) - 0.5f * fsqrt(t_safe);
    float inter = lens ? lens_area : (contained ? PIF * rmin * rmin : 0.0f);
    float uni = PIF * (r0s + r1s) - inter;
    float iou = inter * frcp(fmaxf(uni, EPSF));

    float alpha = fast_acos(fminf(rdiff * frcp(d), ACLIPF));  // arg >= 0 always
    float h2 = d2 - rdiff * rdiff;
    float h2_safe = contained ? 1.0f : fmaxf(h2, EPSF);
    float hull_open = rmax * rmax * (PIF - alpha) + rmin * rmin * alpha
                      + (rmax + rmin) * fsqrt(h2_safe);
    float hull = contained ? PIF * rmax * rmax : hull_open;

    return 1.0f - (iou - (hull - uni) * frcp(fmaxf(hull, EPSF)));
}

__global__ __launch_bounds__(256)
void GIOULOSS_19524921327670_kernel(const float4* __restrict__ x4,
                                    const float4* __restrict__ y4,
                                    float* __restrict__ out, int ngroups) {
    int g = blockIdx.x * blockDim.x + threadIdx.x;
    float acc = 0.0f;
    if (g < ngroups) {
        // 4 elements (12 floats) per thread via 3 coalesced float4 loads each input
        float4 xa = x4[3 * g + 0], xb = x4[3 * g + 1], xc = x4[3 * g + 2];
        float4 ya = y4[3 * g + 0], yb = y4[3 * g + 1], yc = y4[3 * g + 2];
        acc += circle_giou(xa.x, xa.y, xa.z,  ya.x, ya.y, ya.z);
        acc += circle_giou(xa.w, xb.x, xb.y,  ya.w, yb.x, yb.y);
        acc += circle_giou(xb.z, xb.w, xc.x,  yb.z, yb.w, yc.x);
        acc += circle_giou(xc.y, xc.z, xc.w,  yc.y, yc.z, yc.w);
    }

    // wave-64 shuffle reduction
    #pragma unroll
    for (int off = 32; off > 0; off >>= 1)
        acc += __shfl_down(acc, off, 64);

    __shared__ float wave_sums[4];  // 256 threads / 64 = 4 waves
    int lane = threadIdx.x & 63;
    int wave = threadIdx.x >> 6;
    if (lane == 0) wave_sums[wave] = acc;
    __syncthreads();
    if (threadIdx.x == 0) {
        float s = wave_sums[0] + wave_sums[1] + wave_sums[2] + wave_sums[3];
        atomicAdd(out, s);
    }
}

extern "C" void kernel_launch(void* const* d_in, const int* in_sizes, int n_in,
                              void* d_out, int out_size, void* d_ws, size_t ws_size,
                              hipStream_t stream) {
    const float4* x4 = (const float4*)d_in[0];
    const float4* y4 = (const float4*)d_in[1];
    float* out = (float*)d_out;

    int n = in_sizes[0] / 3;          // number of circle pairs (4194304)
    int ngroups = n / 4;              // 4 elements per thread (N divisible by 4)

    hipMemsetAsync(out, 0, sizeof(float), stream);

    int block = 256;
    int grid = (ngroups + block - 1) / block;
    GIOULOSS_19524921327670_kernel<<<grid, block, 0, stream>>>(x4, y4, out, ngroups);
}

// Round 3
// 115.498 us; speedup vs baseline: 1.3105x; 1.3001x over previous
//
#include <hip/hip_runtime.h>
#include <math.h>

// Circle GIoU loss, summed over N pairs.
// x, y: (N,3) float32 row-major [cx, cy, r]. Output: scalar float32 sum.
//
// R3: 8 elements/thread in 2 software-pipelined batches (12 float4 loads
// issued up-front -> compute batch0 overlaps batch1's loads), block partials
// to d_ws, tiny stage-2 reduction kernel (no same-address atomics, no memset).

#define EPSF   1e-07f
#define ACLIPF (1.0f - 1e-06f)
#define PIF    3.14159265358979323846f

__device__ __forceinline__ float frcp(float x)  { return __builtin_amdgcn_rcpf(x); }
__device__ __forceinline__ float fsqrt(float x) { return __builtin_amdgcn_sqrtf(x); }

// Abramowitz & Stegun 4.4.45: acos(x) ~ sqrt(1-x)*poly(x); abs err < 6.7e-5
__device__ __forceinline__ float fast_acos(float x) {
    float ax = fabsf(x);
    float p = fmaf(fmaf(fmaf(-0.0187293f, ax, 0.0742610f), ax, -0.2121144f), ax, 1.5707288f);
    float r = fsqrt(1.0f - ax) * p;
    return x < 0.0f ? PIF - r : r;
}

__device__ __forceinline__ float circle_giou(float cx0, float cy0, float r0,
                                             float cx1, float cy1, float r1) {
    float dx = cx0 - cx1, dy = cy0 - cy1;
    float d2 = fmaf(dx, dx, dy * dy);
    float d  = fsqrt(fmaxf(d2, EPSF));
    float rmax = fmaxf(r0, r1), rmin = fminf(r0, r1);
    float rdiff = rmax - rmin, rsum = r0 + r1;
    bool lens      = (d < rsum) && (d > rdiff);
    bool contained = (d <= rdiff);

    float r0s = r0 * r0, r1s = r1 * r1;
    float inv0 = frcp(fmaxf(2.0f * d * r0, EPSF));
    float inv1 = frcp(fmaxf(2.0f * d * r1, EPSF));
    float cos0 = fminf(fmaxf((d2 + r0s - r1s) * inv0, -ACLIPF), ACLIPF);
    float cos1 = fminf(fmaxf((d2 + r1s - r0s) * inv1, -ACLIPF), ACLIPF);

    float t = (rsum * rsum - d2) * (d2 - rdiff * rdiff);
    float t_safe = lens ? fmaxf(t, EPSF) : 1.0f;
    float lens_area = r0s * fast_acos(cos0) + r1s * fast_acos(cos1) - 0.5f * fsqrt(t_safe);
    float inter = lens ? lens_area : (contained ? PIF * rmin * rmin : 0.0f);
    float uni = PIF * (r0s + r1s) - inter;
    float iou = inter * frcp(fmaxf(uni, EPSF));

    float alpha = fast_acos(fminf(rdiff * frcp(d), ACLIPF));
    float h2 = d2 - rdiff * rdiff;
    float h2_safe = contained ? 1.0f : fmaxf(h2, EPSF);
    float hull_open = rmax * rmax * (PIF - alpha) + rmin * rmin * alpha
                      + (rmax + rmin) * fsqrt(h2_safe);
    float hull = contained ? PIF * rmax * rmax : hull_open;

    return 1.0f - (iou - (hull - uni) * frcp(fmaxf(hull, EPSF)));
}

__device__ __forceinline__ float giou4(float4 xa, float4 xb, float4 xc,
                                       float4 ya, float4 yb, float4 yc) {
    float s = 0.0f;
    s += circle_giou(xa.x, xa.y, xa.z,  ya.x, ya.y, ya.z);
    s += circle_giou(xa.w, xb.x, xb.y,  ya.w, yb.x, yb.y);
    s += circle_giou(xb.z, xb.w, xc.x,  yb.z, yb.w, yc.x);
    s += circle_giou(xc.y, xc.z, xc.w,  yc.y, yc.z, yc.w);
    return s;
}

__global__ __launch_bounds__(256)
void GIOULOSS_19524921327670_stage1(const float4* __restrict__ x4,
                                    const float4* __restrict__ y4,
                                    float* __restrict__ partial, int nthreads) {
    int t = blockIdx.x * blockDim.x + threadIdx.x;
    int g0 = t, g1 = t + nthreads;  // two coalesced halves

    // Issue ALL loads first so batch-1 loads overlap batch-0 compute.
    float4 xa0 = x4[3 * g0 + 0], xb0 = x4[3 * g0 + 1], xc0 = x4[3 * g0 + 2];
    float4 ya0 = y4[3 * g0 + 0], yb0 = y4[3 * g0 + 1], yc0 = y4[3 * g0 + 2];
    float4 xa1 = x4[3 * g1 + 0], xb1 = x4[3 * g1 + 1], xc1 = x4[3 * g1 + 2];
    float4 ya1 = y4[3 * g1 + 0], yb1 = y4[3 * g1 + 1], yc1 = y4[3 * g1 + 2];

    float acc = giou4(xa0, xb0, xc0, ya0, yb0, yc0)
              + giou4(xa1, xb1, xc1, ya1, yb1, yc1);

    #pragma unroll
    for (int off = 32; off > 0; off >>= 1)
        acc += __shfl_down(acc, off, 64);

    __shared__ float wave_sums[4];
    int lane = threadIdx.x & 63;
    int wave = threadIdx.x >> 6;
    if (lane == 0) wave_sums[wave] = acc;
    __syncthreads();
    if (threadIdx.x == 0)
        partial[blockIdx.x] = wave_sums[0] + wave_sums[1] + wave_sums[2] + wave_sums[3];
}

// Sums `nblocks` (=2048) partials with one 256-thread block.
__global__ __launch_bounds__(256)
void GIOULOSS_19524921327670_stage2(const float* __restrict__ partial,
                                    float* __restrict__ out) {
    const float4* p4 = (const float4*)partial;       // 2048 floats = 512 float4
    float4 a = p4[threadIdx.x];
    float4 b = p4[threadIdx.x + 256];
    float acc = (a.x + a.y) + (a.z + a.w) + (b.x + b.y) + (b.z + b.w);

    #pragma unroll
    for (int off = 32; off > 0; off >>= 1)
        acc += __shfl_down(acc, off, 64);

    __shared__ float wave_sums[4];
    int lane = threadIdx.x & 63;
    int wave = threadIdx.x >> 6;
    if (lane == 0) wave_sums[wave] = acc;
    __syncthreads();
    if (threadIdx.x == 0)
        out[0] = wave_sums[0] + wave_sums[1] + wave_sums[2] + wave_sums[3];
}

extern "C" void kernel_launch(void* const* d_in, const int* in_sizes, int n_in,
                              void* d_out, int out_size, void* d_ws, size_t ws_size,
                              hipStream_t stream) {
    const float4* x4 = (const float4*)d_in[0];
    const float4* y4 = (const float4*)d_in[1];
    float* out = (float*)d_out;
    float* partial = (float*)d_ws;

    int n = in_sizes[0] / 3;      // 4194304 circle pairs
    int ngroups = n / 4;          // 1048576 groups of 4
    int nthreads = ngroups / 2;   // 524288 threads, 2 groups each
    int block = 256;
    int grid = nthreads / block;  // 2048 blocks

    GIOULOSS_19524921327670_stage1<<<grid, block, 0, stream>>>(x4, y4, partial, nthreads);
    GIOULOSS_19524921327670_stage2<<<1, block, 0, stream>>>(partial, out);
}